// Round 7
// baseline (225.023 us; speedup 1.0000x reference)
//
#include <hip/hip_runtime.h>
#include <cstddef>

#define NB 64
#define NQ 64
#define NK 8192
#define ND 64
#define K1_KPB 256      // K1: k per block (4 waves x 64 k)
#define KT 256          // K2: k per block (4 chunks of 64)

typedef __attribute__((ext_vector_type(8))) short short8_t;
typedef __attribute__((ext_vector_type(4))) float float4_t;
typedef __attribute__((ext_vector_type(8))) unsigned short ushort8_t;
typedef __attribute__((ext_vector_type(4))) unsigned short ushort4_t;

static __device__ __forceinline__ unsigned short f2bf(float f) {
    unsigned b = __float_as_uint(f);
    b += 0x7FFFu + ((b >> 16) & 1u);          // RNE
    return (unsigned short)(b >> 16);
}
static __device__ __forceinline__ float bf2f(unsigned short u) {
    return __uint_as_float(((unsigned)u) << 16);
}

// ---------------------------------------------------------------------------
// Kernel 1: MFMA QK^T (bf16 hi/lo split: hi*hi + hi*lo + lo*hi) + inverted
// softmax. Block = (b, 256-k tile), 4 waves x 64 k, subtiles of 16 k.
// D[k,q] = sum_d K[k,d]*Q[q,d] via mfma_f32_16x16x32_bf16:
//   A (K rows): lane holds A[row=l&15][kk=(l>>4)*8+j] -> direct global load
//   B (Q^T):    lane holds B[kk=(l>>4)*8+j][col=l&15] = Q[q=l&15+16n][d]
//   C/D: col(q)=lane&15, row(k)=(lane>>4)*4+reg   [HW-verified mapping]
// Softmax over q per k-column: in-lane over n + shfl_xor(1,2,4,8).
// Stores unnormalized p (bf16 in ws, or fp32 fallback) + rowsum atomics.
// ---------------------------------------------------------------------------
template<bool BF16P>
__global__ __launch_bounds__(256, 3) void k_qk_mfma(
    const float* __restrict__ query,
    const float* __restrict__ key,
    void* __restrict__ pstore,
    float* __restrict__ rowsum)
{
    // Q fragments hi/lo, idx16 = l*72 + n*16 + dh*8 + j (stride 72: 16B-aligned)
    __shared__ unsigned short Qhi[64 * 72];
    __shared__ unsigned short Qlo[64 * 72];

    const int tid  = threadIdx.x;
    const int b    = blockIdx.y;
    const int k0   = blockIdx.x * K1_KPB;
    const int lane = tid & 63;
    const int w    = tid >> 6;
    const int lq   = lane & 15;     // q (col) / A row component
    const int lg   = lane >> 4;     // k-octet / reg-group component

    // ---- stage Q fragments: 512 d-octets, 2 per thread, coalesced reads
    {
        const float* qb = query + (size_t)b * NQ * ND;
#pragma unroll
        for (int i = 0; i < 2; ++i) {
            const int o  = tid + 256 * i;     // 0..511
            const int q  = o >> 3;
            const int d0 = (o & 7) * 8;
            float f[8];
            *reinterpret_cast<float4*>(f)     = *reinterpret_cast<const float4*>(qb + q * ND + d0);
            *reinterpret_cast<float4*>(f + 4) = *reinterpret_cast<const float4*>(qb + q * ND + d0 + 4);
            const int n    = q >> 4;
            const int l    = (q & 15) | (((d0 >> 3) & 3) << 4);
            const int dh   = d0 >> 5;
            const int base = l * 72 + n * 16 + dh * 8;
            ushort4_t h[2], lo4[2];
#pragma unroll
            for (int half = 0; half < 2; ++half)
#pragma unroll
                for (int j = 0; j < 4; ++j) {
                    const float fv = f[half * 4 + j];
                    const unsigned u = __float_as_uint(fv);
                    h[half][j] = (unsigned short)(u >> 16);               // trunc hi
                    const float lof = fv - __uint_as_float(u & 0xFFFF0000u);
                    lo4[half][j] = (unsigned short)(__float_as_uint(lof) >> 16);
                }
            *reinterpret_cast<ushort4_t*>(&Qhi[base])     = h[0];
            *reinterpret_cast<ushort4_t*>(&Qhi[base + 4]) = h[1];
            *reinterpret_cast<ushort4_t*>(&Qlo[base])     = lo4[0];
            *reinterpret_cast<ushort4_t*>(&Qlo[base + 4]) = lo4[1];
        }
    }
    __syncthreads();

    // ---- Q fragments -> registers (reused by all 4 subtiles)
    short8_t bhi[4][2], blo[4][2];
#pragma unroll
    for (int n = 0; n < 4; ++n)
#pragma unroll
        for (int dh = 0; dh < 2; ++dh) {
            const int base = lane * 72 + n * 16 + dh * 8;
            bhi[n][dh] = *reinterpret_cast<const short8_t*>(&Qhi[base]);
            blo[n][dh] = *reinterpret_cast<const short8_t*>(&Qlo[base]);
        }

    float rsacc[4] = {0.f, 0.f, 0.f, 0.f};

#pragma unroll 1
    for (int s = 0; s < 4; ++s) {
        const int kbase = k0 + w * 64 + s * 16;

        // A fragments: K rows direct from global (coalesced 16 rows x 256B)
        const float* kr = key + ((size_t)b * NK + kbase + lq) * ND + lg * 8;
        short8_t ahi[2], alo[2];
#pragma unroll
        for (int dh = 0; dh < 2; ++dh) {
            float f[8];
            *reinterpret_cast<float4*>(f)     = *reinterpret_cast<const float4*>(kr + dh * 32);
            *reinterpret_cast<float4*>(f + 4) = *reinterpret_cast<const float4*>(kr + dh * 32 + 4);
#pragma unroll
            for (int j = 0; j < 8; ++j) {
                const unsigned u = __float_as_uint(f[j]);
                ahi[dh][j] = (short)(u >> 16);
                const float lof = f[j] - __uint_as_float(u & 0xFFFF0000u);
                alo[dh][j] = (short)(__float_as_uint(lof) >> 16);
            }
        }

        float4_t acc[4];
#pragma unroll
        for (int n = 0; n < 4; ++n) acc[n] = (float4_t){0.f, 0.f, 0.f, 0.f};

#pragma unroll
        for (int n = 0; n < 4; ++n)
#pragma unroll
            for (int dh = 0; dh < 2; ++dh) {
                acc[n] = __builtin_amdgcn_mfma_f32_16x16x32_bf16(ahi[dh], bhi[n][dh], acc[n], 0, 0, 0);
                acc[n] = __builtin_amdgcn_mfma_f32_16x16x32_bf16(ahi[dh], blo[n][dh], acc[n], 0, 0, 0);
                acc[n] = __builtin_amdgcn_mfma_f32_16x16x32_bf16(alo[dh], bhi[n][dh], acc[n], 0, 0, 0);
            }

        // ---- softmax over all 64 q per k-row r
        float m[4], z[4];
#pragma unroll
        for (int r = 0; r < 4; ++r) {
            m[r] = fmaxf(fmaxf(acc[0][r], acc[1][r]), fmaxf(acc[2][r], acc[3][r]));
            m[r] = fmaxf(m[r], __shfl_xor(m[r], 1, 64));
            m[r] = fmaxf(m[r], __shfl_xor(m[r], 2, 64));
            m[r] = fmaxf(m[r], __shfl_xor(m[r], 4, 64));
            m[r] = fmaxf(m[r], __shfl_xor(m[r], 8, 64));
            z[r] = 0.f;
        }
#pragma unroll
        for (int n = 0; n < 4; ++n)
#pragma unroll
            for (int r = 0; r < 4; ++r) {
                acc[n][r] = __expf((acc[n][r] - m[r]) * 0.125f);   // 1/sqrt(64) folded
                z[r] += acc[n][r];
            }
#pragma unroll
        for (int r = 0; r < 4; ++r) {
            z[r] += __shfl_xor(z[r], 1, 64);
            z[r] += __shfl_xor(z[r], 2, 64);
            z[r] += __shfl_xor(z[r], 4, 64);
            z[r] += __shfl_xor(z[r], 8, 64);
            z[r] = 1.f / z[r];
        }

        // ---- store unnormalized p; rowsum partial from stored (rounded) values
#pragma unroll
        for (int n = 0; n < 4; ++n) {
            const int q = lq + 16 * n;
            float rs = 0.f;
            if (BF16P) {
                ushort4_t u;
#pragma unroll
                for (int r = 0; r < 4; ++r) {
                    const unsigned short us = f2bf(acc[n][r] * z[r]);
                    u[r] = us;
                    rs += bf2f(us);
                }
                *reinterpret_cast<ushort4_t*>((unsigned short*)pstore +
                    ((size_t)(b * NQ + q)) * NK + kbase + lg * 4) = u;
            } else {
                float pf[4];
#pragma unroll
                for (int r = 0; r < 4; ++r) { pf[r] = acc[n][r] * z[r]; rs += pf[r]; }
                *reinterpret_cast<float4*>((float*)pstore +
                    ((size_t)(b * NQ + q)) * NK + kbase + lg * 4) = *reinterpret_cast<float4*>(pf);
            }
            rs += __shfl_xor(rs, 16, 64);       // reduce over the 4 k-octets
            rs += __shfl_xor(rs, 32, 64);
            rsacc[n] += rs;
        }
    }

    if (lg == 0) {
#pragma unroll
        for (int n = 0; n < 4; ++n)
            atomicAdd(&rowsum[b * NQ + lq + 16 * n], rsacc[n]);
    }
}

// ---------------------------------------------------------------------------
// Kernel 2: per (b, 256-k tile), 4 chunks of 64 k. T14 issue-early/write-late:
// chunk c+1's global loads are issued right after chunk c's LDS-write phase,
// in flight during chunk c's PV compute. Scales p by 1/(rowsum+eps), writes
// FINAL attn, PV-accumulates, 16 atomicAdd/thread into zeroed out.
// ---------------------------------------------------------------------------
template<bool BF16P>
__global__ __launch_bounds__(256, 4) void k_scale_pv(
    const float* __restrict__ value,
    const float* __restrict__ rowsum,
    const void* __restrict__ psrc,
    float* __restrict__ attn,
    float* __restrict__ out)
{
    __shared__ alignas(16) float Ps[64 * 68];
    __shared__ alignas(16) float Vs[64 * 64];
    __shared__ float invs[NQ];

    const int b   = blockIdx.y;
    const int k0  = blockIdx.x * KT;
    const int tid = threadIdx.x;

    if (tid < NQ) invs[tid] = 1.f / (rowsum[b * NQ + tid] + 1e-8f);

    const int tq = tid >> 4;
    const int td = tid & 15;

    float acc[4][4];
#pragma unroll
    for (int qi = 0; qi < 4; ++qi)
#pragma unroll
        for (int e = 0; e < 4; ++e) acc[qi][e] = 0.f;

    ushort8_t rp[2];
    float4 rpf[4];
    float4 rv[4];

    // ---- prologue: load chunk 0 into regs
    if (BF16P) {
        const unsigned short* pb = (const unsigned short*)psrc;
#pragma unroll
        for (int i = 0; i < 2; ++i) {
            const int idx = tid + 256 * i;
            const int q   = idx >> 3;
            const int k8  = (idx & 7) * 8;
            rp[i] = *reinterpret_cast<const ushort8_t*>(
                &pb[((size_t)(b * NQ + q)) * NK + k0 + k8]);
        }
    } else {
        const float* pf = (const float*)psrc;
#pragma unroll
        for (int i = 0; i < 4; ++i) {
            const int idx = tid + 256 * i;
            const int q   = idx >> 4;
            const int c4  = (idx & 15) * 4;
            rpf[i] = *reinterpret_cast<const float4*>(
                &pf[((size_t)(b * NQ + q)) * NK + k0 + c4]);
        }
    }
#pragma unroll
    for (int i = 0; i < 4; ++i) {
        const int idx = tid + 256 * i;
        rv[i] = *reinterpret_cast<const float4*>(
            &value[((size_t)b * NK + k0 + (idx >> 4)) * ND + (idx & 15) * 4]);
    }

#pragma unroll 1
    for (int kc = 0; kc < KT; kc += 64) {
        __syncthreads();   // invs ready (iter 0) / previous PV reads done

        // ---- write phase: consume regs -> attn global + Ps/Vs LDS
        if (BF16P) {
#pragma unroll
            for (int i = 0; i < 2; ++i) {
                const int idx = tid + 256 * i;
                const int q   = idx >> 3;
                const int k8  = (idx & 7) * 8;
                const float iv = invs[q];
                float f[8];
#pragma unroll
                for (int j = 0; j < 8; ++j) f[j] = bf2f(rp[i][j]) * iv;
                const size_t gi = ((size_t)(b * NQ + q)) * NK + (size_t)(k0 + kc + k8);
                *reinterpret_cast<float4*>(&attn[gi])     = *reinterpret_cast<float4*>(f);
                *reinterpret_cast<float4*>(&attn[gi + 4]) = *reinterpret_cast<float4*>(f + 4);
                *reinterpret_cast<float4*>(&Ps[q * 68 + k8])     = *reinterpret_cast<float4*>(f);
                *reinterpret_cast<float4*>(&Ps[q * 68 + k8 + 4]) = *reinterpret_cast<float4*>(f + 4);
            }
        } else {
#pragma unroll
            for (int i = 0; i < 4; ++i) {
                const int idx = tid + 256 * i;
                const int q   = idx >> 4;
                const int c4  = (idx & 15) * 4;
                const float iv = invs[q];
                float4 p = rpf[i];
                p.x *= iv; p.y *= iv; p.z *= iv; p.w *= iv;
                const size_t gi = ((size_t)(b * NQ + q)) * NK + (size_t)(k0 + kc + c4);
                *reinterpret_cast<float4*>(&attn[gi]) = p;
                *reinterpret_cast<float4*>(&Ps[q * 68 + c4]) = p;
            }
        }
#pragma unroll
        for (int i = 0; i < 4; ++i) {
            const int idx = tid + 256 * i;
            *reinterpret_cast<float4*>(&Vs[(idx >> 4) * 64 + (idx & 15) * 4]) = rv[i];
        }

        // ---- issue next chunk's loads (fly during PV compute below)
        if (kc + 64 < KT) {
            const int kn = k0 + kc + 64;
            if (BF16P) {
                const unsigned short* pb = (const unsigned short*)psrc;
#pragma unroll
                for (int i = 0; i < 2; ++i) {
                    const int idx = tid + 256 * i;
                    const int q   = idx >> 3;
                    const int k8  = (idx & 7) * 8;
                    rp[i] = *reinterpret_cast<const ushort8_t*>(
                        &pb[((size_t)(b * NQ + q)) * NK + kn + k8]);
                }
            } else {
                const float* pf = (const float*)psrc;
#pragma unroll
                for (int i = 0; i < 4; ++i) {
                    const int idx = tid + 256 * i;
                    const int q   = idx >> 4;
                    const int c4  = (idx & 15) * 4;
                    rpf[i] = *reinterpret_cast<const float4*>(
                        &pf[((size_t)(b * NQ + q)) * NK + kn + c4]);
                }
            }
#pragma unroll
            for (int i = 0; i < 4; ++i) {
                const int idx = tid + 256 * i;
                rv[i] = *reinterpret_cast<const float4*>(
                    &value[((size_t)b * NK + kn + (idx >> 4)) * ND + (idx & 15) * 4]);
            }
        }
        __syncthreads();   // LDS ready

        // ---- PV compute (covers in-flight loads)
#pragma unroll 4
        for (int kq = 0; kq < 16; ++kq) {
            float pqa[4][4];
#pragma unroll
            for (int qi = 0; qi < 4; ++qi)
                *reinterpret_cast<float4*>(pqa[qi]) =
                    *reinterpret_cast<const float4*>(&Ps[(4 * tq + qi) * 68 + 4 * kq]);
#pragma unroll
            for (int kk = 0; kk < 4; ++kk) {
                float vv[4];
                *reinterpret_cast<float4*>(vv) =
                    *reinterpret_cast<const float4*>(&Vs[(4 * kq + kk) * 64 + 4 * td]);
#pragma unroll
                for (int qi = 0; qi < 4; ++qi)
#pragma unroll
                    for (int e = 0; e < 4; ++e)
                        acc[qi][e] = fmaf(pqa[qi][kk], vv[e], acc[qi][e]);
            }
        }
    }

#pragma unroll
    for (int qi = 0; qi < 4; ++qi) {
        float* op = out + ((size_t)(b * NQ + tq * 4 + qi)) * ND + 4 * td;
#pragma unroll
        for (int e = 0; e < 4; ++e) atomicAdd(op + e, acc[qi][e]);
    }
}

extern "C" void kernel_launch(void* const* d_in, const int* in_sizes, int n_in,
                              void* d_out, int out_size, void* d_ws, size_t ws_size,
                              hipStream_t stream) {
    const float* query = (const float*)d_in[0];
    const float* key   = (const float*)d_in[1];
    const float* value = (const float*)d_in[2];

    float* out  = (float*)d_out;                        // [B,Q,D]
    float* attn = (float*)d_out + (size_t)NB * NQ * ND; // [B,Q,K]
    float* rowsum = (float*)d_ws;                       // [B,Q] (16 KB)

    const size_t PB_BYTES = (size_t)NB * NQ * NK * sizeof(unsigned short); // 64 MiB
    const bool bf16p = ws_size >= 16384 + PB_BYTES;
    void* pbuf = bf16p ? (void*)((char*)d_ws + 16384) : (void*)attn;

    hipMemsetAsync(rowsum, 0, (size_t)NB * NQ * sizeof(float), stream);
    hipMemsetAsync(out, 0, (size_t)NB * NQ * ND * sizeof(float), stream);

    dim3 g1(NK / K1_KPB, NB);
    dim3 g2(NK / KT, NB);
    if (bf16p) {
        k_qk_mfma<true><<<g1, 256, 0, stream>>>(query, key, pbuf, rowsum);
        k_scale_pv<true><<<g2, 256, 0, stream>>>(value, rowsum, pbuf, attn, out);
    } else {
        k_qk_mfma<false><<<g1, 256, 0, stream>>>(query, key, pbuf, rowsum);
        k_scale_pv<false><<<g2, 256, 0, stream>>>(value, rowsum, pbuf, attn, out);
    }
}

// Round 8
// 153.131 us; speedup vs baseline: 1.4695x; 1.4695x over previous
//
#include <hip/hip_runtime.h>
#include <cstddef>

#define NB 64
#define NQ 64
#define NK 8192
#define ND 64
#define KPB 256            // k per block, both MFMA kernels (4 waves x 64 k)
#define NSLICE (NK / KPB)  // 32 partial slices per b

typedef __attribute__((ext_vector_type(8))) short short8_t;
typedef __attribute__((ext_vector_type(4))) float float4_t;
typedef __attribute__((ext_vector_type(4))) unsigned short ushort4_t;

static __device__ __forceinline__ unsigned short f2bf(float f) {
    unsigned b = __float_as_uint(f);
    b += 0x7FFFu + ((b >> 16) & 1u);          // RNE
    return (unsigned short)(b >> 16);
}
static __device__ __forceinline__ void split8(const float* f, short8_t& hi, short8_t& lo) {
#pragma unroll
    for (int j = 0; j < 8; ++j) {
        const unsigned u = __float_as_uint(f[j]);
        hi[j] = (short)(u >> 16);
        const float lof = f[j] - __uint_as_float(u & 0xFFFF0000u);
        lo[j] = (short)(__float_as_uint(lof) >> 16);
    }
}

// ---------------------------------------------------------------------------
// Pass A: rowsum only. MFMA QK^T (bf16 hi/lo split) + inverted softmax,
// atomicAdd rowsum[b,q] (fp32, unrounded). Reads K once, writes 16 KB.
// D[k,q]: A = K rows (lane: row=l&15, k-octet (l>>4)*8+j), B = Q^T frags.
// C/D: col(q)=lane&15 (+16n), row(k)=(lane>>4)*4+reg (+16s).
// ---------------------------------------------------------------------------
__global__ __launch_bounds__(256, 3) void k_qk_rowsum(
    const float* __restrict__ query,
    const float* __restrict__ key,
    float* __restrict__ rowsum)
{
    __shared__ alignas(16) unsigned short Qhi[64 * 72];
    __shared__ alignas(16) unsigned short Qlo[64 * 72];

    const int tid  = threadIdx.x;
    const int b    = blockIdx.y;
    const int k0   = blockIdx.x * KPB;
    const int lane = tid & 63;
    const int w    = tid >> 6;
    const int lq   = lane & 15;
    const int lg   = lane >> 4;

    // stage Q fragments hi/lo (coalesced reads, frag-layout LDS writes)
    {
        const float* qb = query + (size_t)b * NQ * ND;
#pragma unroll
        for (int i = 0; i < 2; ++i) {
            const int o  = tid + 256 * i;
            const int q  = o >> 3;
            const int d0 = (o & 7) * 8;
            float f[8];
            *reinterpret_cast<float4*>(f)     = *reinterpret_cast<const float4*>(qb + q * ND + d0);
            *reinterpret_cast<float4*>(f + 4) = *reinterpret_cast<const float4*>(qb + q * ND + d0 + 4);
            short8_t h, l8;
            split8(f, h, l8);
            const int n    = q >> 4;
            const int l    = (q & 15) | (((d0 >> 3) & 3) << 4);
            const int dh   = d0 >> 5;
            const int base = l * 72 + n * 16 + dh * 8;
            *reinterpret_cast<short8_t*>(&Qhi[base]) = h;
            *reinterpret_cast<short8_t*>(&Qlo[base]) = l8;
        }
    }
    __syncthreads();

    short8_t bhi[4][2], blo[4][2];
#pragma unroll
    for (int n = 0; n < 4; ++n)
#pragma unroll
        for (int dh = 0; dh < 2; ++dh) {
            const int base = lane * 72 + n * 16 + dh * 8;
            bhi[n][dh] = *reinterpret_cast<const short8_t*>(&Qhi[base]);
            blo[n][dh] = *reinterpret_cast<const short8_t*>(&Qlo[base]);
        }

    float rsacc[4] = {0.f, 0.f, 0.f, 0.f};

#pragma unroll 1
    for (int s = 0; s < 4; ++s) {
        const int kbase = k0 + w * 64 + s * 16;
        const float* kr = key + ((size_t)b * NK + kbase + lq) * ND + lg * 8;
        short8_t ahi[2], alo[2];
#pragma unroll
        for (int dh = 0; dh < 2; ++dh) {
            float f[8];
            *reinterpret_cast<float4*>(f)     = *reinterpret_cast<const float4*>(kr + dh * 32);
            *reinterpret_cast<float4*>(f + 4) = *reinterpret_cast<const float4*>(kr + dh * 32 + 4);
            split8(f, ahi[dh], alo[dh]);
        }

        float4_t acc[4];
#pragma unroll
        for (int n = 0; n < 4; ++n) acc[n] = (float4_t){0.f, 0.f, 0.f, 0.f};
#pragma unroll
        for (int n = 0; n < 4; ++n)
#pragma unroll
            for (int dh = 0; dh < 2; ++dh) {
                acc[n] = __builtin_amdgcn_mfma_f32_16x16x32_bf16(ahi[dh], bhi[n][dh], acc[n], 0, 0, 0);
                acc[n] = __builtin_amdgcn_mfma_f32_16x16x32_bf16(ahi[dh], blo[n][dh], acc[n], 0, 0, 0);
                acc[n] = __builtin_amdgcn_mfma_f32_16x16x32_bf16(alo[dh], bhi[n][dh], acc[n], 0, 0, 0);
            }

        float m[4], z[4];
#pragma unroll
        for (int r = 0; r < 4; ++r) {
            m[r] = fmaxf(fmaxf(acc[0][r], acc[1][r]), fmaxf(acc[2][r], acc[3][r]));
            m[r] = fmaxf(m[r], __shfl_xor(m[r], 1, 64));
            m[r] = fmaxf(m[r], __shfl_xor(m[r], 2, 64));
            m[r] = fmaxf(m[r], __shfl_xor(m[r], 4, 64));
            m[r] = fmaxf(m[r], __shfl_xor(m[r], 8, 64));
            z[r] = 0.f;
        }
#pragma unroll
        for (int n = 0; n < 4; ++n)
#pragma unroll
            for (int r = 0; r < 4; ++r) {
                acc[n][r] = __expf((acc[n][r] - m[r]) * 0.125f);
                z[r] += acc[n][r];
            }
#pragma unroll
        for (int r = 0; r < 4; ++r) {
            z[r] += __shfl_xor(z[r], 1, 64);
            z[r] += __shfl_xor(z[r], 2, 64);
            z[r] += __shfl_xor(z[r], 4, 64);
            z[r] += __shfl_xor(z[r], 8, 64);
            z[r] = 1.f / z[r];
        }
#pragma unroll
        for (int n = 0; n < 4; ++n) {
            float rs = 0.f;
#pragma unroll
            for (int r = 0; r < 4; ++r) rs += acc[n][r] * z[r];
            rs += __shfl_xor(rs, 16, 64);
            rs += __shfl_xor(rs, 32, 64);
            rsacc[n] += rs;
        }
    }

    if (lg == 0) {
#pragma unroll
        for (int n = 0; n < 4; ++n)
            atomicAdd(&rowsum[b * NQ + lq + 16 * n], rsacc[n]);
    }
}

// ---------------------------------------------------------------------------
// Pass B: recompute QK^T (identical MFMA sequence -> bit-identical p),
// scale by invz*invrow, write FINAL fp32 attn, pack p_final to bf16 in LDS,
// then PV via MFMA: wave w owns d-cols [16w,16w+16) over the block's 256 k
// (no cross-wave overlap), writes deterministic per-block partials. No atomics.
// LDS: SH 33 KB (Q-frag staging aliased with p tile) + rsL.
// ---------------------------------------------------------------------------
__global__ __launch_bounds__(256, 3) void k_attn_pv_mfma(
    const float* __restrict__ query,
    const float* __restrict__ key,
    const float* __restrict__ value,
    const float* __restrict__ rowsum,
    float* __restrict__ attn,
    float* __restrict__ partials)
{
    __shared__ alignas(16) unsigned short SH[64 * 264];   // 33792 B
    __shared__ float rsL[64];

    const int tid  = threadIdx.x;
    const int b    = blockIdx.y;
    const int k0   = blockIdx.x * KPB;
    const int lane = tid & 63;
    const int w    = tid >> 6;
    const int lq   = lane & 15;
    const int lg   = lane >> 4;

    unsigned short* Qhi = SH;
    unsigned short* Qlo = SH + 64 * 72;

    {
        const float* qb = query + (size_t)b * NQ * ND;
#pragma unroll
        for (int i = 0; i < 2; ++i) {
            const int o  = tid + 256 * i;
            const int q  = o >> 3;
            const int d0 = (o & 7) * 8;
            float f[8];
            *reinterpret_cast<float4*>(f)     = *reinterpret_cast<const float4*>(qb + q * ND + d0);
            *reinterpret_cast<float4*>(f + 4) = *reinterpret_cast<const float4*>(qb + q * ND + d0 + 4);
            short8_t h, l8;
            split8(f, h, l8);
            const int n    = q >> 4;
            const int l    = (q & 15) | (((d0 >> 3) & 3) << 4);
            const int dh   = d0 >> 5;
            const int base = l * 72 + n * 16 + dh * 8;
            *reinterpret_cast<short8_t*>(&Qhi[base]) = h;
            *reinterpret_cast<short8_t*>(&Qlo[base]) = l8;
        }
    }
    if (tid < 64) rsL[tid] = 1.f / (rowsum[b * NQ + tid] + 1e-8f);
    __syncthreads();

    short8_t bhi[4][2], blo[4][2];
#pragma unroll
    for (int n = 0; n < 4; ++n)
#pragma unroll
        for (int dh = 0; dh < 2; ++dh) {
            const int base = lane * 72 + n * 16 + dh * 8;
            bhi[n][dh] = *reinterpret_cast<const short8_t*>(&Qhi[base]);
            blo[n][dh] = *reinterpret_cast<const short8_t*>(&Qlo[base]);
        }
    __syncthreads();                       // Q frags in regs -> SH reusable

    unsigned short* pL = SH;               // p tile [64 q][264 pitch], cols=256 k
    float invr[4];
#pragma unroll
    for (int n = 0; n < 4; ++n) invr[n] = rsL[16 * n + lq];

    // ---- QK^T + softmax + attn write + p pack (wave's own 64-k slice)
#pragma unroll 1
    for (int s = 0; s < 4; ++s) {
        const int kbase = k0 + w * 64 + s * 16;
        const float* kr = key + ((size_t)b * NK + kbase + lq) * ND + lg * 8;
        short8_t ahi[2], alo[2];
#pragma unroll
        for (int dh = 0; dh < 2; ++dh) {
            float f[8];
            *reinterpret_cast<float4*>(f)     = *reinterpret_cast<const float4*>(kr + dh * 32);
            *reinterpret_cast<float4*>(f + 4) = *reinterpret_cast<const float4*>(kr + dh * 32 + 4);
            split8(f, ahi[dh], alo[dh]);
        }

        float4_t acc[4];
#pragma unroll
        for (int n = 0; n < 4; ++n) acc[n] = (float4_t){0.f, 0.f, 0.f, 0.f};
#pragma unroll
        for (int n = 0; n < 4; ++n)
#pragma unroll
            for (int dh = 0; dh < 2; ++dh) {
                acc[n] = __builtin_amdgcn_mfma_f32_16x16x32_bf16(ahi[dh], bhi[n][dh], acc[n], 0, 0, 0);
                acc[n] = __builtin_amdgcn_mfma_f32_16x16x32_bf16(ahi[dh], blo[n][dh], acc[n], 0, 0, 0);
                acc[n] = __builtin_amdgcn_mfma_f32_16x16x32_bf16(alo[dh], bhi[n][dh], acc[n], 0, 0, 0);
            }

        float m[4], z[4];
#pragma unroll
        for (int r = 0; r < 4; ++r) {
            m[r] = fmaxf(fmaxf(acc[0][r], acc[1][r]), fmaxf(acc[2][r], acc[3][r]));
            m[r] = fmaxf(m[r], __shfl_xor(m[r], 1, 64));
            m[r] = fmaxf(m[r], __shfl_xor(m[r], 2, 64));
            m[r] = fmaxf(m[r], __shfl_xor(m[r], 4, 64));
            m[r] = fmaxf(m[r], __shfl_xor(m[r], 8, 64));
            z[r] = 0.f;
        }
#pragma unroll
        for (int n = 0; n < 4; ++n)
#pragma unroll
            for (int r = 0; r < 4; ++r) {
                acc[n][r] = __expf((acc[n][r] - m[r]) * 0.125f);
                z[r] += acc[n][r];
            }
#pragma unroll
        for (int r = 0; r < 4; ++r) {
            z[r] += __shfl_xor(z[r], 1, 64);
            z[r] += __shfl_xor(z[r], 2, 64);
            z[r] += __shfl_xor(z[r], 4, 64);
            z[r] += __shfl_xor(z[r], 8, 64);
            z[r] = 1.f / z[r];
        }

#pragma unroll
        for (int n = 0; n < 4; ++n) {
            float pf[4];
            ushort4_t u;
#pragma unroll
            for (int r = 0; r < 4; ++r) {
                pf[r] = acc[n][r] * z[r] * invr[n];   // FINAL attn value, fp32
                u[r]  = f2bf(pf[r]);
            }
            *reinterpret_cast<float4*>(attn +
                ((size_t)(b * NQ + 16 * n + lq)) * NK + kbase + lg * 4) =
                *reinterpret_cast<float4*>(pf);
            *reinterpret_cast<ushort4_t*>(
                &pL[(16 * n + lq) * 264 + (kbase - k0) + lg * 4]) = u;
        }
    }
    __syncthreads();   // full p tile [64 q][256 k] packed

    // ---- PV via MFMA: out[q, 16w+lq] over block's 256 k.
    // A = p (lane: row q=l&15 (+16n), k-octet (l>>4)*8+j), B = V hi/lo.
    float4_t oacc[4];
#pragma unroll
    for (int n = 0; n < 4; ++n) oacc[n] = (float4_t){0.f, 0.f, 0.f, 0.f};

#pragma unroll 2
    for (int t = 0; t < 8; ++t) {
        const float* vp = value + ((size_t)b * NK + k0 + t * 32 + lg * 8) * ND + 16 * w + lq;
        float vf[8];
#pragma unroll
        for (int j = 0; j < 8; ++j) vf[j] = vp[(size_t)j * ND];
        short8_t vhi, vlo;
        split8(vf, vhi, vlo);

        short8_t pa[4];
#pragma unroll
        for (int n = 0; n < 4; ++n)
            pa[n] = *reinterpret_cast<const short8_t*>(
                &pL[(16 * n + lq) * 264 + t * 32 + lg * 8]);
#pragma unroll
        for (int n = 0; n < 4; ++n) {
            oacc[n] = __builtin_amdgcn_mfma_f32_16x16x32_bf16(pa[n], vhi, oacc[n], 0, 0, 0);
            oacc[n] = __builtin_amdgcn_mfma_f32_16x16x32_bf16(pa[n], vlo, oacc[n], 0, 0, 0);
        }
    }

    // partial[b][slice][q][d]; D layout: row q = 16n+4lg+r, col d = 16w+lq
    float* pb = partials + ((size_t)(b * NSLICE + blockIdx.x)) * (NQ * ND);
#pragma unroll
    for (int n = 0; n < 4; ++n)
#pragma unroll
        for (int r = 0; r < 4; ++r)
            pb[(16 * n + 4 * lg + r) * ND + 16 * w + lq] = oacc[n][r];
}

// ---------------------------------------------------------------------------
// Reduce: out[b,q,d] = sum over 32 slices of partial[b][s][q][d].
// grid (4, NB): each block sums 256 float4s.
// ---------------------------------------------------------------------------
__global__ __launch_bounds__(256) void k_reduce_out(
    const float* __restrict__ partials,
    float* __restrict__ out)
{
    const int b   = blockIdx.y;
    const int idx = blockIdx.x * 256 + threadIdx.x;    // 0..1023 float4 per b
    const float4* pb = reinterpret_cast<const float4*>(partials + (size_t)b * NSLICE * NQ * ND);
    float4 sum = make_float4(0.f, 0.f, 0.f, 0.f);
#pragma unroll
    for (int s = 0; s < NSLICE; ++s) {
        const float4 v = pb[(size_t)s * (NQ * ND / 4) + idx];
        sum.x += v.x; sum.y += v.y; sum.z += v.z; sum.w += v.w;
    }
    reinterpret_cast<float4*>(out + (size_t)b * NQ * ND)[idx] = sum;
}

extern "C" void kernel_launch(void* const* d_in, const int* in_sizes, int n_in,
                              void* d_out, int out_size, void* d_ws, size_t ws_size,
                              hipStream_t stream) {
    const float* query = (const float*)d_in[0];
    const float* key   = (const float*)d_in[1];
    const float* value = (const float*)d_in[2];

    float* out  = (float*)d_out;                        // [B,Q,D]
    float* attn = (float*)d_out + (size_t)NB * NQ * ND; // [B,Q,K]
    float* rowsum   = (float*)d_ws;                                  // 16 KB pad
    float* partials = (float*)((char*)d_ws + 16384);                 // 33.5 MB

    hipMemsetAsync(rowsum, 0, (size_t)NB * NQ * sizeof(float), stream);

    dim3 g(NK / KPB, NB);
    k_qk_rowsum<<<g, 256, 0, stream>>>(query, key, rowsum);
    k_attn_pv_mfma<<<g, 256, 0, stream>>>(query, key, value, rowsum, attn, partials);
    k_reduce_out<<<dim3(4, NB), 256, 0, stream>>>(partials, out);
}

// Round 9
// 147.169 us; speedup vs baseline: 1.5290x; 1.0405x over previous
//
#include <hip/hip_runtime.h>
#include <cstddef>

#define NB 64
#define NQ 64
#define NK 8192
#define ND 64
#define KPB 256            // k per block, both MFMA kernels (4 waves x 64 k)
#define NSLICE (NK / KPB)  // 32 partial slices per b

typedef __attribute__((ext_vector_type(8))) short short8_t;
typedef __attribute__((ext_vector_type(4))) float float4_t;
typedef __attribute__((ext_vector_type(4))) unsigned short ushort4_t;

static __device__ __forceinline__ unsigned short f2bf(float f) {
    unsigned b = __float_as_uint(f);
    b += 0x7FFFu + ((b >> 16) & 1u);          // RNE
    return (unsigned short)(b >> 16);
}
static __device__ __forceinline__ void split8(const float* f, short8_t& hi, short8_t& lo) {
#pragma unroll
    for (int j = 0; j < 8; ++j) {
        const unsigned u = __float_as_uint(f[j]);
        hi[j] = (short)(u >> 16);
        const float lof = f[j] - __uint_as_float(u & 0xFFFF0000u);
        lo[j] = (short)(__float_as_uint(lof) >> 16);
    }
}

// ---------------------------------------------------------------------------
// Pass A: rowsum only. MFMA QK^T (bf16 hi/lo split) + inverted softmax,
// atomicAdd rowsum[b,q]. Reads K once (near HBM floor, ~24 us) — unchanged
// from round 7.
// ---------------------------------------------------------------------------
__global__ __launch_bounds__(256, 3) void k_qk_rowsum(
    const float* __restrict__ query,
    const float* __restrict__ key,
    float* __restrict__ rowsum)
{
    __shared__ alignas(16) unsigned short Qhi[64 * 72];
    __shared__ alignas(16) unsigned short Qlo[64 * 72];

    const int tid  = threadIdx.x;
    const int b    = blockIdx.y;
    const int k0   = blockIdx.x * KPB;
    const int lane = tid & 63;
    const int w    = tid >> 6;
    const int lq   = lane & 15;
    const int lg   = lane >> 4;

    {
        const float* qb = query + (size_t)b * NQ * ND;
#pragma unroll
        for (int i = 0; i < 2; ++i) {
            const int o  = tid + 256 * i;
            const int q  = o >> 3;
            const int d0 = (o & 7) * 8;
            float f[8];
            *reinterpret_cast<float4*>(f)     = *reinterpret_cast<const float4*>(qb + q * ND + d0);
            *reinterpret_cast<float4*>(f + 4) = *reinterpret_cast<const float4*>(qb + q * ND + d0 + 4);
            short8_t h, l8;
            split8(f, h, l8);
            const int n    = q >> 4;
            const int l    = (q & 15) | (((d0 >> 3) & 3) << 4);
            const int dh   = d0 >> 5;
            const int base = l * 72 + n * 16 + dh * 8;
            *reinterpret_cast<short8_t*>(&Qhi[base]) = h;
            *reinterpret_cast<short8_t*>(&Qlo[base]) = l8;
        }
    }
    __syncthreads();

    short8_t bhi[4][2], blo[4][2];
#pragma unroll
    for (int n = 0; n < 4; ++n)
#pragma unroll
        for (int dh = 0; dh < 2; ++dh) {
            const int base = lane * 72 + n * 16 + dh * 8;
            bhi[n][dh] = *reinterpret_cast<const short8_t*>(&Qhi[base]);
            blo[n][dh] = *reinterpret_cast<const short8_t*>(&Qlo[base]);
        }

    float rsacc[4] = {0.f, 0.f, 0.f, 0.f};

#pragma unroll 1
    for (int s = 0; s < 4; ++s) {
        const int kbase = k0 + w * 64 + s * 16;
        const float* kr = key + ((size_t)b * NK + kbase + lq) * ND + lg * 8;
        short8_t ahi[2], alo[2];
#pragma unroll
        for (int dh = 0; dh < 2; ++dh) {
            float f[8];
            *reinterpret_cast<float4*>(f)     = *reinterpret_cast<const float4*>(kr + dh * 32);
            *reinterpret_cast<float4*>(f + 4) = *reinterpret_cast<const float4*>(kr + dh * 32 + 4);
            split8(f, ahi[dh], alo[dh]);
        }

        float4_t acc[4];
#pragma unroll
        for (int n = 0; n < 4; ++n) acc[n] = (float4_t){0.f, 0.f, 0.f, 0.f};
#pragma unroll
        for (int n = 0; n < 4; ++n)
#pragma unroll
            for (int dh = 0; dh < 2; ++dh) {
                acc[n] = __builtin_amdgcn_mfma_f32_16x16x32_bf16(ahi[dh], bhi[n][dh], acc[n], 0, 0, 0);
                acc[n] = __builtin_amdgcn_mfma_f32_16x16x32_bf16(ahi[dh], blo[n][dh], acc[n], 0, 0, 0);
                acc[n] = __builtin_amdgcn_mfma_f32_16x16x32_bf16(alo[dh], bhi[n][dh], acc[n], 0, 0, 0);
            }

        float m[4], z[4];
#pragma unroll
        for (int r = 0; r < 4; ++r) {
            m[r] = fmaxf(fmaxf(acc[0][r], acc[1][r]), fmaxf(acc[2][r], acc[3][r]));
            m[r] = fmaxf(m[r], __shfl_xor(m[r], 1, 64));
            m[r] = fmaxf(m[r], __shfl_xor(m[r], 2, 64));
            m[r] = fmaxf(m[r], __shfl_xor(m[r], 4, 64));
            m[r] = fmaxf(m[r], __shfl_xor(m[r], 8, 64));
            z[r] = 0.f;
        }
#pragma unroll
        for (int n = 0; n < 4; ++n)
#pragma unroll
            for (int r = 0; r < 4; ++r) {
                acc[n][r] = __expf((acc[n][r] - m[r]) * 0.125f);
                z[r] += acc[n][r];
            }
#pragma unroll
        for (int r = 0; r < 4; ++r) {
            z[r] += __shfl_xor(z[r], 1, 64);
            z[r] += __shfl_xor(z[r], 2, 64);
            z[r] += __shfl_xor(z[r], 4, 64);
            z[r] += __shfl_xor(z[r], 8, 64);
            z[r] = 1.f / z[r];
        }
#pragma unroll
        for (int n = 0; n < 4; ++n) {
            float rs = 0.f;
#pragma unroll
            for (int r = 0; r < 4; ++r) rs += acc[n][r] * z[r];
            rs += __shfl_xor(rs, 16, 64);
            rs += __shfl_xor(rs, 32, 64);
            rsacc[n] += rs;
        }
    }

    if (lg == 0) {
#pragma unroll
        for (int n = 0; n < 4; ++n)
            atomicAdd(&rowsum[b * NQ + lq + 16 * n], rsacc[n]);
    }
}

// ---------------------------------------------------------------------------
// Pass B: recompute QK^T via MFMA (K loads software-pipelined across the
// s-loop), write FINAL fp32 attn + pack bf16 p into LDS; then PV via MFMA
// with V staged through LDS: V chunk prefetched into regs (chunk 0 issued at
// kernel start, covered by QK^T), transposed 4x4 in regs, stored pre-split
// bf16 hi/lo [d][kk] pitch 72 with d-row XOR swizzle (read = bank-uniform
// ds_read_b128). Deterministic per-block partials; no out atomics.
// LDS: SH 33 KB (Q frags / p tile) + Vhi/Vlo 18 KB + rsL = 52.5 KB -> 3 blk/CU.
// ---------------------------------------------------------------------------
__global__ __launch_bounds__(256, 3) void k_attn_pv_mfma(
    const float* __restrict__ query,
    const float* __restrict__ key,
    const float* __restrict__ value,
    const float* __restrict__ rowsum,
    float* __restrict__ attn,
    float* __restrict__ partials)
{
    __shared__ alignas(16) unsigned short SH[64 * 264];    // Q frags, then p tile
    __shared__ alignas(16) unsigned short Vhi[64 * 72];    // [d^swz][kk] bf16 hi
    __shared__ alignas(16) unsigned short Vlo[64 * 72];    // [d^swz][kk] bf16 lo
    __shared__ float rsL[64];

    const int tid  = threadIdx.x;
    const int b    = blockIdx.y;
    const int k0   = blockIdx.x * KPB;
    const int lane = tid & 63;
    const int w    = tid >> 6;
    const int lq   = lane & 15;
    const int lg   = lane >> 4;

    unsigned short* Qhi = SH;
    unsigned short* Qlo = SH + 64 * 72;

    // ---- V chunk-0 prefetch (in flight during Q staging + QK^T phase)
    const int vk4 = (tid >> 4) * 4;          // kk rows this thread transposes
    const int vd4 = (tid & 15) * 4;          // d cols
    const float4* vg = reinterpret_cast<const float4*>(value + ((size_t)b * NK + k0) * ND);
    float vt[4][4];
#pragma unroll
    for (int r = 0; r < 4; ++r)
        *reinterpret_cast<float4*>(vt[r]) = vg[(vk4 + r) * 16 + (vd4 >> 2)];

    // ---- stage Q fragments hi/lo
    {
        const float* qb = query + (size_t)b * NQ * ND;
#pragma unroll
        for (int i = 0; i < 2; ++i) {
            const int o  = tid + 256 * i;
            const int q  = o >> 3;
            const int d0 = (o & 7) * 8;
            float f[8];
            *reinterpret_cast<float4*>(f)     = *reinterpret_cast<const float4*>(qb + q * ND + d0);
            *reinterpret_cast<float4*>(f + 4) = *reinterpret_cast<const float4*>(qb + q * ND + d0 + 4);
            short8_t h, l8;
            split8(f, h, l8);
            const int n    = q >> 4;
            const int l    = (q & 15) | (((d0 >> 3) & 3) << 4);
            const int dh   = d0 >> 5;
            const int base = l * 72 + n * 16 + dh * 8;
            *reinterpret_cast<short8_t*>(&Qhi[base]) = h;
            *reinterpret_cast<short8_t*>(&Qlo[base]) = l8;
        }
    }
    if (tid < 64) rsL[tid] = 1.f / (rowsum[b * NQ + tid] + 1e-8f);

    // ---- K subtile-0 preload (regs)
    float kf[16];
    {
        const float* kr = key + ((size_t)b * NK + k0 + w * 64 + lq) * ND + lg * 8;
        *reinterpret_cast<float4*>(kf)      = *reinterpret_cast<const float4*>(kr);
        *reinterpret_cast<float4*>(kf + 4)  = *reinterpret_cast<const float4*>(kr + 4);
        *reinterpret_cast<float4*>(kf + 8)  = *reinterpret_cast<const float4*>(kr + 32);
        *reinterpret_cast<float4*>(kf + 12) = *reinterpret_cast<const float4*>(kr + 36);
    }
    __syncthreads();

    short8_t bhi[4][2], blo[4][2];
#pragma unroll
    for (int n = 0; n < 4; ++n)
#pragma unroll
        for (int dh = 0; dh < 2; ++dh) {
            const int base = lane * 72 + n * 16 + dh * 8;
            bhi[n][dh] = *reinterpret_cast<const short8_t*>(&Qhi[base]);
            blo[n][dh] = *reinterpret_cast<const short8_t*>(&Qlo[base]);
        }
    __syncthreads();                       // Q frags in regs -> SH reusable

    unsigned short* pL = SH;               // p tile [64 q][264 pitch], cols=256 k
    float invr[4];
#pragma unroll
    for (int n = 0; n < 4; ++n) invr[n] = rsL[16 * n + lq];

    // ---- QK^T + softmax + attn write + p pack, K pipelined across subtiles
#pragma unroll 1
    for (int s = 0; s < 4; ++s) {
        const int kbase = k0 + w * 64 + s * 16;

        short8_t ahi[2], alo[2];
        split8(kf, ahi[0], alo[0]);
        split8(kf + 8, ahi[1], alo[1]);

        if (s < 3) {   // issue next subtile's K loads; fly under MFMA+softmax
            const float* kr = key + ((size_t)b * NK + kbase + 16 + lq) * ND + lg * 8;
            *reinterpret_cast<float4*>(kf)      = *reinterpret_cast<const float4*>(kr);
            *reinterpret_cast<float4*>(kf + 4)  = *reinterpret_cast<const float4*>(kr + 4);
            *reinterpret_cast<float4*>(kf + 8)  = *reinterpret_cast<const float4*>(kr + 32);
            *reinterpret_cast<float4*>(kf + 12) = *reinterpret_cast<const float4*>(kr + 36);
        }

        float4_t acc[4];
#pragma unroll
        for (int n = 0; n < 4; ++n) acc[n] = (float4_t){0.f, 0.f, 0.f, 0.f};
#pragma unroll
        for (int n = 0; n < 4; ++n)
#pragma unroll
            for (int dh = 0; dh < 2; ++dh) {
                acc[n] = __builtin_amdgcn_mfma_f32_16x16x32_bf16(ahi[dh], bhi[n][dh], acc[n], 0, 0, 0);
                acc[n] = __builtin_amdgcn_mfma_f32_16x16x32_bf16(ahi[dh], blo[n][dh], acc[n], 0, 0, 0);
                acc[n] = __builtin_amdgcn_mfma_f32_16x16x32_bf16(alo[dh], bhi[n][dh], acc[n], 0, 0, 0);
            }

        float m[4], z[4];
#pragma unroll
        for (int r = 0; r < 4; ++r) {
            m[r] = fmaxf(fmaxf(acc[0][r], acc[1][r]), fmaxf(acc[2][r], acc[3][r]));
            m[r] = fmaxf(m[r], __shfl_xor(m[r], 1, 64));
            m[r] = fmaxf(m[r], __shfl_xor(m[r], 2, 64));
            m[r] = fmaxf(m[r], __shfl_xor(m[r], 4, 64));
            m[r] = fmaxf(m[r], __shfl_xor(m[r], 8, 64));
            z[r] = 0.f;
        }
#pragma unroll
        for (int n = 0; n < 4; ++n)
#pragma unroll
            for (int r = 0; r < 4; ++r) {
                acc[n][r] = __expf((acc[n][r] - m[r]) * 0.125f);
                z[r] += acc[n][r];
            }
#pragma unroll
        for (int r = 0; r < 4; ++r) {
            z[r] += __shfl_xor(z[r], 1, 64);
            z[r] += __shfl_xor(z[r], 2, 64);
            z[r] += __shfl_xor(z[r], 4, 64);
            z[r] += __shfl_xor(z[r], 8, 64);
            z[r] = 1.f / z[r];
        }

#pragma unroll
        for (int n = 0; n < 4; ++n) {
            float pf[4];
            ushort4_t u;
#pragma unroll
            for (int r = 0; r < 4; ++r) {
                pf[r] = acc[n][r] * z[r] * invr[n];   // FINAL attn value, fp32
                u[r]  = f2bf(pf[r]);
            }
            *reinterpret_cast<float4*>(attn +
                ((size_t)(b * NQ + 16 * n + lq)) * NK + kbase + lg * 4) =
                *reinterpret_cast<float4*>(pf);
            *reinterpret_cast<ushort4_t*>(
                &pL[(16 * n + lq) * 264 + (kbase - k0) + lg * 4]) = u;
        }
    }

    // ---- PV via MFMA over 4 chunks of 64 k. V: regs -> transposed split LDS.
    float4_t oacc[4];
#pragma unroll
    for (int n = 0; n < 4; ++n) oacc[n] = (float4_t){0.f, 0.f, 0.f, 0.f};

#pragma unroll 1
    for (int c = 0; c < 4; ++c) {
        // stage vt (chunk c) -> Vhi/Vlo: 4x4 reg transpose, b64 stores,
        // d-row swizzle m = d ^ ((kk>>3)&3)
        const int ms = (vk4 >> 3) & 3;
#pragma unroll
        for (int j = 0; j < 4; ++j) {
            ushort4_t h4, l4;
#pragma unroll
            for (int r = 0; r < 4; ++r) {
                const unsigned uu = __float_as_uint(vt[r][j]);
                h4[r] = (unsigned short)(uu >> 16);
                const float lof = vt[r][j] - __uint_as_float(uu & 0xFFFF0000u);
                l4[r] = (unsigned short)(__float_as_uint(lof) >> 16);
            }
            const int mrow = (vd4 + j) ^ ms;
            *reinterpret_cast<ushort4_t*>(&Vhi[mrow * 72 + vk4]) = h4;
            *reinterpret_cast<ushort4_t*>(&Vlo[mrow * 72 + vk4]) = l4;
        }
        if (c < 3) {   // issue next chunk's V loads; fly under this chunk's MFMA
#pragma unroll
            for (int r = 0; r < 4; ++r)
                *reinterpret_cast<float4*>(vt[r]) =
                    vg[((c + 1) * 64 + vk4 + r) * 16 + (vd4 >> 2)];
        }
        __syncthreads();   // Vhi/Vlo ready (and pL complete, c==0)

#pragma unroll
        for (int h = 0; h < 2; ++h) {
            const int mrow = (16 * w + (lq ^ lg)) * 72;   // d=16w+lq, swz by lg
            const short8_t vhi8 = *reinterpret_cast<const short8_t*>(&Vhi[mrow + h * 32 + lg * 8]);
            const short8_t vlo8 = *reinterpret_cast<const short8_t*>(&Vlo[mrow + h * 32 + lg * 8]);
#pragma unroll
            for (int n = 0; n < 4; ++n) {
                const short8_t pa = *reinterpret_cast<const short8_t*>(
                    &pL[(16 * n + lq) * 264 + c * 64 + h * 32 + lg * 8]);
                oacc[n] = __builtin_amdgcn_mfma_f32_16x16x32_bf16(pa, vhi8, oacc[n], 0, 0, 0);
                oacc[n] = __builtin_amdgcn_mfma_f32_16x16x32_bf16(pa, vlo8, oacc[n], 0, 0, 0);
            }
        }
        __syncthreads();   // Vhi/Vlo consumed before next chunk's stores
    }

    // partial[b][slice][q][d]; D layout: row q = 16n+4lg+r, col d = 16w+lq
    float* pb = partials + ((size_t)(b * NSLICE + blockIdx.x)) * (NQ * ND);
#pragma unroll
    for (int n = 0; n < 4; ++n)
#pragma unroll
        for (int r = 0; r < 4; ++r)
            pb[(16 * n + 4 * lg + r) * ND + 16 * w + lq] = oacc[n][r];
}

// ---------------------------------------------------------------------------
// Reduce: out[b,q,d] = sum over 32 slices of partial[b][s][q][d].
// ---------------------------------------------------------------------------
__global__ __launch_bounds__(256) void k_reduce_out(
    const float* __restrict__ partials,
    float* __restrict__ out)
{
    const int b   = blockIdx.y;
    const int idx = blockIdx.x * 256 + threadIdx.x;    // 0..1023 float4 per b
    const float4* pb = reinterpret_cast<const float4*>(partials + (size_t)b * NSLICE * NQ * ND);
    float4 sum = make_float4(0.f, 0.f, 0.f, 0.f);
#pragma unroll
    for (int s = 0; s < NSLICE; ++s) {
        const float4 v = pb[(size_t)s * (NQ * ND / 4) + idx];
        sum.x += v.x; sum.y += v.y; sum.z += v.z; sum.w += v.w;
    }
    reinterpret_cast<float4*>(out + (size_t)b * NQ * ND)[idx] = sum;
}

extern "C" void kernel_launch(void* const* d_in, const int* in_sizes, int n_in,
                              void* d_out, int out_size, void* d_ws, size_t ws_size,
                              hipStream_t stream) {
    const float* query = (const float*)d_in[0];
    const float* key   = (const float*)d_in[1];
    const float* value = (const float*)d_in[2];

    float* out  = (float*)d_out;                        // [B,Q,D]
    float* attn = (float*)d_out + (size_t)NB * NQ * ND; // [B,Q,K]
    float* rowsum   = (float*)d_ws;                     // 16 KB pad
    float* partials = (float*)((char*)d_ws + 16384);    // 33.5 MB

    hipMemsetAsync(rowsum, 0, (size_t)NB * NQ * sizeof(float), stream);

    dim3 g(NK / KPB, NB);
    k_qk_rowsum<<<g, 256, 0, stream>>>(query, key, rowsum);
    k_attn_pv_mfma<<<g, 256, 0, stream>>>(query, key, value, rowsum, attn, partials);
    k_reduce_out<<<dim3(4, NB), 256, 0, stream>>>(partials, out);
}